// Round 1
// baseline (4375.203 us; speedup 1.0000x reference)
//
#include <hip/hip_runtime.h>
#include <hip/hip_bf16.h>
#include <math.h>

#define B_SZ 4096
#define L_SZ 512
#define A_SZ 64
#define HD_SZ 1024
#define H_SZ 32

typedef __attribute__((ext_vector_type(8))) short bf16x8;
typedef __attribute__((ext_vector_type(4))) short s16x4;
typedef __attribute__((ext_vector_type(4))) float f32x4;

union frag_u { bf16x8 v; s16x4 h[2]; };

#define GLDS16(gsrc, ldst) __builtin_amdgcn_global_load_lds(              \
    (const __attribute__((address_space(1))) void*)(gsrc),                \
    (__attribute__((address_space(3))) void*)(ldst), 16, 0, 0)

__device__ __forceinline__ float gelu_exact(float x) {
  return 0.5f * x * (1.0f + erff(x * 0.70710678118654752f));
}

// ---------------------------------------------------------------------------
// GEMM: C[M,N] = A[M,K] (bf16, row-major, possibly two-source split on K)
//              x W[K,N] given as Wt[N,K] bf16 (pre-transposed)
// 4 waves (2x2), each wave computes (BM/2)x(BN/2) via 16x16x32 bf16 MFMA.
// MODE 0: out_f32 = acc + bias[n]
// MODE 1: dz = acc + bias; zn = z_cur + gs*dz; write z_cur, znb(bf16),
//         traj[m*(H*L) + t*L + n] (d_out slice)
// MODE 2: out_b = bf16(gelu(acc + bias))
// ---------------------------------------------------------------------------
template <int BM, int BN, int MODE>
__global__ __launch_bounds__(256) void gemm_kernel(
    const __hip_bfloat16* __restrict__ A0, int a0s,
    const __hip_bfloat16* __restrict__ A1, int a1s, int ksplit,
    const __hip_bfloat16* __restrict__ Bt,
    const float* __restrict__ bias,
    int N, int K,
    float* __restrict__ outf,
    float* __restrict__ z_cur,
    __hip_bfloat16* __restrict__ znb,
    float* __restrict__ traj,
    const float* __restrict__ gate,
    int t,
    __hip_bfloat16* __restrict__ outb) {
  constexpr int BK = 32;
  constexpr int FM = BM / 32, FN = BN / 32;
  __shared__ __align__(16) __hip_bfloat16 lds[(BM + BN) * BK];
  __hip_bfloat16* ldsA = lds;
  __hip_bfloat16* ldsB = lds + BM * BK;

  const int tid = threadIdx.x;
  const int m0 = blockIdx.x * BM, n0 = blockIdx.y * BN;
  const int wave = tid >> 6, lane = tid & 63;
  const int l15 = lane & 15, lg = lane >> 4;
  const int wm = wave >> 1, wn = wave & 1;

  f32x4 acc[FM][FN];
#pragma unroll
  for (int mi = 0; mi < FM; ++mi)
#pragma unroll
    for (int ni = 0; ni < FN; ++ni) acc[mi][ni] = (f32x4){0.f, 0.f, 0.f, 0.f};

  for (int k0 = 0; k0 < K; k0 += BK) {
    __syncthreads();
    // ---- stage A tile [BM][32] (XOR-swizzled byte cols, linear LDS dest) --
    const __hip_bfloat16* Aptr;
    int As, kloc;
    if (k0 < ksplit) { Aptr = A0; As = a0s; kloc = k0; }
    else             { Aptr = A1; As = a1s; kloc = k0 - ksplit; }
#pragma unroll
    for (int i = 0; i < BM / 64; ++i) {
      int off = tid * 16 + i * 4096;          // byte offset in tile
      int r = off >> 6, c = off & 63;
      int csw = c ^ ((r & 3) << 4);
      const __hip_bfloat16* src = Aptr + (size_t)(m0 + r) * As + kloc + (csw >> 1);
      GLDS16(src, ldsA + (off >> 1));
    }
    // ---- stage B tile [BN][32] from Wt rows ------------------------------
#pragma unroll
    for (int i = 0; i < BN / 64; ++i) {
      int off = tid * 16 + i * 4096;
      int r = off >> 6, c = off & 63;
      int csw = c ^ ((r & 3) << 4);
      const __hip_bfloat16* src = Bt + (size_t)(n0 + r) * K + k0 + (csw >> 1);
      GLDS16(src, ldsB + (off >> 1));
    }
    asm volatile("s_waitcnt vmcnt(0)" ::: "memory");
    __syncthreads();

    // ---- fragments + MFMA ------------------------------------------------
    frag_u af[FM], bf[FN];
#pragma unroll
    for (int mi = 0; mi < FM; ++mi) {
      int row = wm * (FM * 16) + mi * 16 + l15;
      int c0 = (lg * 8) ^ ((row & 3) << 4);
      int c1 = (lg * 8 + 32) ^ ((row & 3) << 4);
      af[mi].h[0] = *(const s16x4*)(ldsA + row * BK + (c0 >> 1));
      af[mi].h[1] = *(const s16x4*)(ldsA + row * BK + (c1 >> 1));
    }
#pragma unroll
    for (int ni = 0; ni < FN; ++ni) {
      int row = wn * (FN * 16) + ni * 16 + l15;
      int c0 = (lg * 8) ^ ((row & 3) << 4);
      int c1 = (lg * 8 + 32) ^ ((row & 3) << 4);
      bf[ni].h[0] = *(const s16x4*)(ldsB + row * BK + (c0 >> 1));
      bf[ni].h[1] = *(const s16x4*)(ldsB + row * BK + (c1 >> 1));
    }
#pragma unroll
    for (int mi = 0; mi < FM; ++mi)
#pragma unroll
      for (int ni = 0; ni < FN; ++ni)
        acc[mi][ni] = __builtin_amdgcn_mfma_f32_16x16x32_bf16(
            af[mi].v, bf[ni].v, acc[mi][ni], 0, 0, 0);
  }

  // ---- epilogue -----------------------------------------------------------
  float gs = 0.f;
  if constexpr (MODE == 1) gs = 1.f / (1.f + expf(-gate[0]));
#pragma unroll
  for (int mi = 0; mi < FM; ++mi) {
#pragma unroll
    for (int ni = 0; ni < FN; ++ni) {
      int gcol = n0 + wn * (FN * 16) + ni * 16 + l15;
      float bv = bias[gcol];
#pragma unroll
      for (int r = 0; r < 4; ++r) {
        int grow = m0 + wm * (FM * 16) + mi * 16 + lg * 4 + r;
        float v = acc[mi][ni][r] + bv;
        if constexpr (MODE == 0) {
          outf[(size_t)grow * N + gcol] = v;
        } else if constexpr (MODE == 1) {
          size_t zi = (size_t)grow * L_SZ + gcol;
          float zn = z_cur[zi] + gs * v;
          z_cur[zi] = zn;
          znb[zi] = __float2bfloat16(zn);
          traj[(size_t)grow * (H_SZ * L_SZ) + (size_t)t * L_SZ + gcol] = zn;
        } else {
          outb[(size_t)grow * N + gcol] = __float2bfloat16(gelu_exact(v));
        }
      }
    }
  }
}

// ---------------------------------------------------------------------------
// Row LayerNorm (N=1024) + GELU, fp32 in -> bf16 out. One block per row.
// ---------------------------------------------------------------------------
__global__ __launch_bounds__(256) void ln_gelu_kernel(
    const float* __restrict__ x, const float* __restrict__ gam,
    const float* __restrict__ bet, __hip_bfloat16* __restrict__ out) {
  constexpr int N = HD_SZ;
  const int row = blockIdx.x;
  const int tid = threadIdx.x, lane = tid & 63, wave = tid >> 6;
  const float* xr = x + (size_t)row * N;
  f32x4 v = *(const f32x4*)(xr + tid * 4);
  float s = v[0] + v[1] + v[2] + v[3];
  float s2 = v[0] * v[0] + v[1] * v[1] + v[2] * v[2] + v[3] * v[3];
#pragma unroll
  for (int o = 32; o; o >>= 1) {
    s += __shfl_xor(s, o);
    s2 += __shfl_xor(s2, o);
  }
  __shared__ float as_[4], as2_[4];
  if (lane == 0) { as_[wave] = s; as2_[wave] = s2; }
  __syncthreads();
  s = as_[0] + as_[1] + as_[2] + as_[3];
  s2 = as2_[0] + as2_[1] + as2_[2] + as2_[3];
  float mean = s * (1.f / N);
  float var = s2 * (1.f / N) - mean * mean;
  float rstd = rsqrtf(var + 1e-5f);
  f32x4 g = *(const f32x4*)(gam + tid * 4);
  f32x4 b = *(const f32x4*)(bet + tid * 4);
  union { __hip_bfloat16 h[4]; s16x4 sv; } o;
#pragma unroll
  for (int j = 0; j < 4; ++j) {
    float y = (v[j] - mean) * rstd * g[j] + b[j];
    o.h[j] = __float2bfloat16(gelu_exact(y));
  }
  *(s16x4*)(out + (size_t)row * N + tid * 4) = o.sv;
}

// ---------------------------------------------------------------------------
// sigma: one wave per row: softplus(dot(u_row[512], uW2) + ub2)
// ---------------------------------------------------------------------------
__global__ __launch_bounds__(256) void sigma_kernel(
    const __hip_bfloat16* __restrict__ ub, const float* __restrict__ uW2,
    const float* __restrict__ ub2, float* __restrict__ sigs, int t) {
  const int row = blockIdx.x * 4 + (threadIdx.x >> 6);
  const int lane = threadIdx.x & 63;
  union { s16x4 sv[2]; __hip_bfloat16 h[8]; } u;
  const s16x4* up = (const s16x4*)(ub + (size_t)row * 512 + lane * 8);
  u.sv[0] = up[0];
  u.sv[1] = up[1];
  f32x4 w0 = *(const f32x4*)(uW2 + lane * 8);
  f32x4 w1 = *(const f32x4*)(uW2 + lane * 8 + 4);
  float d = 0.f;
#pragma unroll
  for (int j = 0; j < 4; ++j) d += __bfloat162float(u.h[j]) * w0[j];
#pragma unroll
  for (int j = 0; j < 4; ++j) d += __bfloat162float(u.h[4 + j]) * w1[j];
#pragma unroll
  for (int o = 32; o; o >>= 1) d += __shfl_xor(d, o);
  if (lane == 0) {
    float v = d + ub2[0];
    sigs[(size_t)row * H_SZ + t] = v > 20.f ? v : log1pf(expf(v));
  }
}

// ---------------------------------------------------------------------------
// prep kernels
// ---------------------------------------------------------------------------
__global__ void transpose_cvt(const float* __restrict__ in,
                              __hip_bfloat16* __restrict__ out, int K, int N) {
  __shared__ float tile[32][33];
  const int n0 = blockIdx.x * 32, k0 = blockIdx.y * 32;
  const int tx = threadIdx.x, ty = threadIdx.y;  // (32, 8)
#pragma unroll
  for (int i = 0; i < 32; i += 8)
    tile[ty + i][tx] = in[(size_t)(k0 + ty + i) * N + (n0 + tx)];
  __syncthreads();
#pragma unroll
  for (int i = 0; i < 32; i += 8)
    out[(size_t)(n0 + ty + i) * K + (k0 + tx)] = __float2bfloat16(tile[tx][ty + i]);
}

__global__ void cvt_bf16_kernel(const float* __restrict__ in,
                                __hip_bfloat16* __restrict__ out, int n4) {
  int i = blockIdx.x * 256 + threadIdx.x;
  if (i >= n4) return;
  f32x4 v = ((const f32x4*)in)[i];
  union { __hip_bfloat16 h[4]; s16x4 sv; } o;
#pragma unroll
  for (int j = 0; j < 4; ++j) o.h[j] = __float2bfloat16(v[j]);
  ((s16x4*)out)[i] = o.sv;
}

__global__ void init_z_kernel(const float* __restrict__ z0,
                              float* __restrict__ z_cur,
                              __hip_bfloat16* __restrict__ znb, int n4) {
  int i = blockIdx.x * 256 + threadIdx.x;
  if (i >= n4) return;
  f32x4 v = ((const f32x4*)z0)[i];
  ((f32x4*)z_cur)[i] = v;
  union { __hip_bfloat16 h[4]; s16x4 sv; } o;
#pragma unroll
  for (int j = 0; j < 4; ++j) o.h[j] = __float2bfloat16(v[j]);
  ((s16x4*)znb)[i] = o.sv;
}

// ---------------------------------------------------------------------------
extern "C" void kernel_launch(void* const* d_in, const int* in_sizes, int n_in,
                              void* d_out, int out_size, void* d_ws,
                              size_t ws_size, hipStream_t stream) {
  const float* z0      = (const float*)d_in[0];
  const float* actions = (const float*)d_in[1];
  const float* W1  = (const float*)d_in[2];
  const float* b1  = (const float*)d_in[3];
  const float* g1  = (const float*)d_in[4];
  const float* be1 = (const float*)d_in[5];
  const float* W2  = (const float*)d_in[6];
  const float* b2  = (const float*)d_in[7];
  const float* g2  = (const float*)d_in[8];
  const float* be2 = (const float*)d_in[9];
  const float* W3  = (const float*)d_in[10];
  const float* b3  = (const float*)d_in[11];
  const float* uW1 = (const float*)d_in[12];
  const float* ub1 = (const float*)d_in[13];
  const float* uW2 = (const float*)d_in[14];
  const float* ub2 = (const float*)d_in[15];
  const float* gate = (const float*)d_in[16];

  char* w = (char*)d_ws;
  __hip_bfloat16* W1t = (__hip_bfloat16*)w;  w += (size_t)(L_SZ + A_SZ) * HD_SZ * 2;
  __hip_bfloat16* W2t = (__hip_bfloat16*)w;  w += (size_t)HD_SZ * HD_SZ * 2;
  __hip_bfloat16* W3t = (__hip_bfloat16*)w;  w += (size_t)HD_SZ * L_SZ * 2;
  __hip_bfloat16* uW1t = (__hip_bfloat16*)w; w += (size_t)L_SZ * (HD_SZ / 2) * 2;
  __hip_bfloat16* actb = (__hip_bfloat16*)w; w += (size_t)B_SZ * H_SZ * A_SZ * 2;
  float* z_cur = (float*)w;                  w += (size_t)B_SZ * L_SZ * 4;
  __hip_bfloat16* znb = (__hip_bfloat16*)w;  w += (size_t)B_SZ * L_SZ * 2;
  float* tws = (float*)w;                    w += (size_t)B_SZ * HD_SZ * 4;
  __hip_bfloat16* hb = (__hip_bfloat16*)w;   w += (size_t)B_SZ * HD_SZ * 2;
  __hip_bfloat16* ubuf = (__hip_bfloat16*)w; w += (size_t)B_SZ * L_SZ * 2;

  float* trajOut = (float*)d_out;
  float* sigsOut = (float*)d_out + (size_t)B_SZ * H_SZ * L_SZ;

  dim3 tb(32, 8);
  transpose_cvt<<<dim3(HD_SZ / 32, (L_SZ + A_SZ) / 32), tb, 0, stream>>>(W1, W1t, L_SZ + A_SZ, HD_SZ);
  transpose_cvt<<<dim3(HD_SZ / 32, HD_SZ / 32), tb, 0, stream>>>(W2, W2t, HD_SZ, HD_SZ);
  transpose_cvt<<<dim3(L_SZ / 32, HD_SZ / 32), tb, 0, stream>>>(W3, W3t, HD_SZ, L_SZ);
  transpose_cvt<<<dim3((HD_SZ / 2) / 32, L_SZ / 32), tb, 0, stream>>>(uW1, uW1t, L_SZ, HD_SZ / 2);

  cvt_bf16_kernel<<<(B_SZ * H_SZ * A_SZ / 4 + 255) / 256, 256, 0, stream>>>(
      actions, actb, B_SZ * H_SZ * A_SZ / 4);
  init_z_kernel<<<(B_SZ * L_SZ / 4 + 255) / 256, 256, 0, stream>>>(
      z0, z_cur, znb, B_SZ * L_SZ / 4);

  const int KSPLIT_NONE = 1 << 30;
  for (int t = 0; t < H_SZ; ++t) {
    // GEMM1: za @ W1 + b1 -> tws   (A = [znb | actions[:,t,:]])
    gemm_kernel<128, 128, 0><<<dim3(B_SZ / 128, HD_SZ / 128), 256, 0, stream>>>(
        znb, L_SZ, actb + (size_t)t * A_SZ, H_SZ * A_SZ, L_SZ, W1t, b1,
        HD_SZ, L_SZ + A_SZ, tws, nullptr, nullptr, nullptr, nullptr, 0, nullptr);
    ln_gelu_kernel<<<B_SZ, 256, 0, stream>>>(tws, g1, be1, hb);
    // GEMM2: h1 @ W2 + b2 -> tws
    gemm_kernel<128, 128, 0><<<dim3(B_SZ / 128, HD_SZ / 128), 256, 0, stream>>>(
        hb, HD_SZ, nullptr, 0, KSPLIT_NONE, W2t, b2,
        HD_SZ, HD_SZ, tws, nullptr, nullptr, nullptr, nullptr, 0, nullptr);
    ln_gelu_kernel<<<B_SZ, 256, 0, stream>>>(tws, g2, be2, hb);
    // GEMM3: h2 @ W3 + b3 -> z update + traj write + znb
    gemm_kernel<64, 128, 1><<<dim3(B_SZ / 64, L_SZ / 128), 256, 0, stream>>>(
        hb, HD_SZ, nullptr, 0, KSPLIT_NONE, W3t, b3,
        L_SZ, HD_SZ, nullptr, z_cur, znb, trajOut, gate, t, nullptr);
    // GEMM4: z_next @ uW1 + ub1 -> gelu -> ubuf (bf16)
    gemm_kernel<64, 128, 2><<<dim3(B_SZ / 64, (HD_SZ / 2) / 128), 256, 0, stream>>>(
        znb, L_SZ, nullptr, 0, KSPLIT_NONE, uW1t, ub1,
        HD_SZ / 2, L_SZ, nullptr, nullptr, nullptr, nullptr, nullptr, 0, ubuf);
    sigma_kernel<<<B_SZ / 4, 256, 0, stream>>>(ubuf, uW2, ub2, sigsOut, t);
  }
}

// Round 2
// 2518.267 us; speedup vs baseline: 1.7374x; 1.7374x over previous
//
#include <hip/hip_runtime.h>
#include <hip/hip_bf16.h>
#include <math.h>

#define B_SZ 4096
#define L_SZ 512
#define A_SZ 64
#define HD_SZ 1024
#define H_SZ 32

typedef __attribute__((ext_vector_type(8))) short bf16x8;
typedef __attribute__((ext_vector_type(4))) short s16x4;
typedef __attribute__((ext_vector_type(4))) float f32x4;

union frag_u { bf16x8 v; s16x4 h[2]; };

#define GLDS16(gsrc, ldst) __builtin_amdgcn_global_load_lds(              \
    (const __attribute__((address_space(1))) void*)(gsrc),                \
    (__attribute__((address_space(3))) void*)(ldst), 16, 0, 0)

__device__ __forceinline__ float gelu_exact(float x) {
  return 0.5f * x * (1.0f + erff(x * 0.70710678118654752f));
}

// ---------------------------------------------------------------------------
// 2-phase double-buffered GEMM: C[M,N] = A[M,K] (bf16) x Wt[N,K] (bf16)
// BK=64, 4 waves (2x2). XOR-swizzled LDS (byte col ^ ((row&7)<<4)).
// MODE 0: outf = acc + bias[n]                                  (f32)
// MODE 1: dz = acc+bias; zn = z_cur + gs*dz; write z_cur, znb, traj slice
// MODE 3: g = gelu(acc+bias); atomicAdd(sig_acc[row*H+t], g*uW2[n]) (fused)
// ---------------------------------------------------------------------------
template <int BM, int BN, int MODE>
__global__ __launch_bounds__(256, 2) void gemm_kernel(
    const __hip_bfloat16* __restrict__ A0, int a0s,
    const __hip_bfloat16* __restrict__ A1, int a1s, int ksplit,
    const __hip_bfloat16* __restrict__ Bt,
    const float* __restrict__ bias,
    int N, int K,
    float* __restrict__ outf,
    float* __restrict__ z_cur,
    __hip_bfloat16* __restrict__ znb,
    float* __restrict__ traj,
    const float* __restrict__ gate,
    int t,
    const float* __restrict__ uW2,
    float* __restrict__ sig_acc) {
  constexpr int BK = 64;
  constexpr int FM = BM / 32, FN = BN / 32;
  constexpr int HALF = (BM + BN) * BK;
  __shared__ __align__(16) __hip_bfloat16 lds[2 * HALF];

  const int tid = threadIdx.x;
  const int m0 = blockIdx.x * BM, n0 = blockIdx.y * BN;
  const int wave = tid >> 6, lane = tid & 63;
  const int l15 = lane & 15, lg = lane >> 4;
  const int wm = wave >> 1, wn = wave & 1;
  const int NK = K / BK;

  f32x4 acc[FM][FN];
#pragma unroll
  for (int mi = 0; mi < FM; ++mi)
#pragma unroll
    for (int ni = 0; ni < FN; ++ni) acc[mi][ni] = (f32x4){0.f, 0.f, 0.f, 0.f};

  auto stage = [&](int buf, int kt) {
    __hip_bfloat16* dA = lds + buf * HALF;
    __hip_bfloat16* dB = dA + BM * BK;
    const int k0 = kt * BK;
    const __hip_bfloat16* Aptr;
    int As, kloc;
    if (k0 < ksplit) { Aptr = A0; As = a0s; kloc = k0; }
    else             { Aptr = A1; As = a1s; kloc = k0 - ksplit; }
#pragma unroll
    for (int i = 0; i < BM / 32; ++i) {
      int off = tid * 16 + i * 4096;          // byte offset in [BM][128B] tile
      int r = off >> 7, c = off & 127;
      int csw = c ^ ((r & 7) << 4);
      GLDS16(Aptr + (size_t)(m0 + r) * As + kloc + (csw >> 1), dA + (off >> 1));
    }
#pragma unroll
    for (int i = 0; i < BN / 32; ++i) {
      int off = tid * 16 + i * 4096;
      int r = off >> 7, c = off & 127;
      int csw = c ^ ((r & 7) << 4);
      GLDS16(Bt + (size_t)(n0 + r) * K + k0 + (csw >> 1), dB + (off >> 1));
    }
  };

  // prologue
  stage(0, 0);
  asm volatile("s_waitcnt vmcnt(0)" ::: "memory");
  __syncthreads();

  int buf = 0;
  for (int kt = 0; kt < NK; ++kt) {
    if (kt + 1 < NK) stage(buf ^ 1, kt + 1);

    const __hip_bfloat16* ldsA = lds + buf * HALF;
    const __hip_bfloat16* ldsB = ldsA + BM * BK;

    frag_u a_[FM][2], b_[FN][2];
#pragma unroll
    for (int mi = 0; mi < FM; ++mi) {
      int row = wm * (FM * 16) + mi * 16 + l15;
      int xr = (row & 7) << 4;
      const char* base = (const char*)(ldsA + row * BK);
#pragma unroll
      for (int s = 0; s < 2; ++s) {
        a_[mi][s].h[0] = *(const s16x4*)(base + ((s * 64 + lg * 8) ^ xr));
        a_[mi][s].h[1] = *(const s16x4*)(base + ((s * 64 + 32 + lg * 8) ^ xr));
      }
    }
#pragma unroll
    for (int ni = 0; ni < FN; ++ni) {
      int row = wn * (FN * 16) + ni * 16 + l15;
      int xr = (row & 7) << 4;
      const char* base = (const char*)(ldsB + row * BK);
#pragma unroll
      for (int s = 0; s < 2; ++s) {
        b_[ni][s].h[0] = *(const s16x4*)(base + ((s * 64 + lg * 8) ^ xr));
        b_[ni][s].h[1] = *(const s16x4*)(base + ((s * 64 + 32 + lg * 8) ^ xr));
      }
    }
#pragma unroll
    for (int s = 0; s < 2; ++s)
#pragma unroll
      for (int mi = 0; mi < FM; ++mi)
#pragma unroll
        for (int ni = 0; ni < FN; ++ni)
          acc[mi][ni] = __builtin_amdgcn_mfma_f32_16x16x32_bf16(
              a_[mi][s].v, b_[ni][s].v, acc[mi][ni], 0, 0, 0);

    asm volatile("s_waitcnt vmcnt(0)" ::: "memory");
    __syncthreads();
    buf ^= 1;
  }

  // ---- epilogue -----------------------------------------------------------
  if constexpr (MODE == 3) {
#pragma unroll
    for (int mi = 0; mi < FM; ++mi) {
      float p[4] = {0.f, 0.f, 0.f, 0.f};
#pragma unroll
      for (int ni = 0; ni < FN; ++ni) {
        int gcol = n0 + wn * (FN * 16) + ni * 16 + l15;
        float bv = bias[gcol];
        float w2 = uW2[gcol];
#pragma unroll
        for (int r = 0; r < 4; ++r)
          p[r] += gelu_exact(acc[mi][ni][r] + bv) * w2;
      }
#pragma unroll
      for (int o = 1; o < 16; o <<= 1) {
#pragma unroll
        for (int r = 0; r < 4; ++r) p[r] += __shfl_xor(p[r], o);
      }
      if (l15 == 0) {
        int rowb = m0 + wm * (FM * 16) + mi * 16 + lg * 4;
#pragma unroll
        for (int r = 0; r < 4; ++r)
          atomicAdd(&sig_acc[(size_t)(rowb + r) * H_SZ + t], p[r]);
      }
    }
  } else {
    float gs = 0.f;
    if constexpr (MODE == 1) gs = 1.f / (1.f + expf(-gate[0]));
#pragma unroll
    for (int mi = 0; mi < FM; ++mi) {
#pragma unroll
      for (int ni = 0; ni < FN; ++ni) {
        int gcol = n0 + wn * (FN * 16) + ni * 16 + l15;
        float bv = bias[gcol];
#pragma unroll
        for (int r = 0; r < 4; ++r) {
          int grow = m0 + wm * (FM * 16) + mi * 16 + lg * 4 + r;
          float v = acc[mi][ni][r] + bv;
          if constexpr (MODE == 0) {
            outf[(size_t)grow * N + gcol] = v;
          } else {
            size_t zi = (size_t)grow * L_SZ + gcol;
            float zn = z_cur[zi] + gs * v;
            z_cur[zi] = zn;
            znb[zi] = __float2bfloat16(zn);
            traj[(size_t)grow * (H_SZ * L_SZ) + (size_t)t * L_SZ + gcol] = zn;
          }
        }
      }
    }
  }
}

// ---------------------------------------------------------------------------
// Row LayerNorm (N=1024) + GELU, fp32 in -> bf16 out. One block per row.
// ---------------------------------------------------------------------------
__global__ __launch_bounds__(256) void ln_gelu_kernel(
    const float* __restrict__ x, const float* __restrict__ gam,
    const float* __restrict__ bet, __hip_bfloat16* __restrict__ out) {
  constexpr int N = HD_SZ;
  const int row = blockIdx.x;
  const int tid = threadIdx.x, lane = tid & 63, wave = tid >> 6;
  const float* xr = x + (size_t)row * N;
  f32x4 v = *(const f32x4*)(xr + tid * 4);
  float s = v[0] + v[1] + v[2] + v[3];
  float s2 = v[0] * v[0] + v[1] * v[1] + v[2] * v[2] + v[3] * v[3];
#pragma unroll
  for (int o = 32; o; o >>= 1) {
    s += __shfl_xor(s, o);
    s2 += __shfl_xor(s2, o);
  }
  __shared__ float as_[4], as2_[4];
  if (lane == 0) { as_[wave] = s; as2_[wave] = s2; }
  __syncthreads();
  s = as_[0] + as_[1] + as_[2] + as_[3];
  s2 = as2_[0] + as2_[1] + as2_[2] + as2_[3];
  float mean = s * (1.f / N);
  float var = s2 * (1.f / N) - mean * mean;
  float rstd = rsqrtf(var + 1e-5f);
  f32x4 g = *(const f32x4*)(gam + tid * 4);
  f32x4 b = *(const f32x4*)(bet + tid * 4);
  union { __hip_bfloat16 h[4]; s16x4 sv; } o;
#pragma unroll
  for (int j = 0; j < 4; ++j) {
    float y = (v[j] - mean) * rstd * g[j] + b[j];
    o.h[j] = __float2bfloat16(gelu_exact(y));
  }
  *(s16x4*)(out + (size_t)row * N + tid * 4) = o.sv;
}

// ---------------------------------------------------------------------------
// prep / misc kernels
// ---------------------------------------------------------------------------
__global__ void transpose_cvt(const float* __restrict__ in,
                              __hip_bfloat16* __restrict__ out, int K, int N) {
  __shared__ float tile[32][33];
  const int n0 = blockIdx.x * 32, k0 = blockIdx.y * 32;
  const int tx = threadIdx.x, ty = threadIdx.y;  // (32, 8)
#pragma unroll
  for (int i = 0; i < 32; i += 8)
    tile[ty + i][tx] = in[(size_t)(k0 + ty + i) * N + (n0 + tx)];
  __syncthreads();
#pragma unroll
  for (int i = 0; i < 32; i += 8)
    out[(size_t)(n0 + ty + i) * K + (k0 + tx)] = __float2bfloat16(tile[tx][ty + i]);
}

__global__ void cvt_bf16_kernel(const float* __restrict__ in,
                                __hip_bfloat16* __restrict__ out, int n4) {
  int i = blockIdx.x * 256 + threadIdx.x;
  if (i >= n4) return;
  f32x4 v = ((const f32x4*)in)[i];
  union { __hip_bfloat16 h[4]; s16x4 sv; } o;
#pragma unroll
  for (int j = 0; j < 4; ++j) o.h[j] = __float2bfloat16(v[j]);
  ((s16x4*)out)[i] = o.sv;
}

__global__ void init_z_kernel(const float* __restrict__ z0,
                              float* __restrict__ z_cur,
                              __hip_bfloat16* __restrict__ znb, int n4) {
  int i = blockIdx.x * 256 + threadIdx.x;
  if (i >= n4) return;
  f32x4 v = ((const f32x4*)z0)[i];
  ((f32x4*)z_cur)[i] = v;
  union { __hip_bfloat16 h[4]; s16x4 sv; } o;
#pragma unroll
  for (int j = 0; j < 4; ++j) o.h[j] = __float2bfloat16(v[j]);
  ((s16x4*)znb)[i] = o.sv;
}

__global__ void zero_kernel(float* __restrict__ p, int n) {
  int i = blockIdx.x * 256 + threadIdx.x;
  if (i < n) p[i] = 0.f;
}

__global__ void softplus_kernel(const float* __restrict__ acc,
                                const float* __restrict__ ub2,
                                float* __restrict__ out, int n) {
  int i = blockIdx.x * 256 + threadIdx.x;
  if (i >= n) return;
  float v = acc[i] + ub2[0];
  out[i] = v > 20.f ? v : log1pf(expf(v));
}

// ---------------------------------------------------------------------------
extern "C" void kernel_launch(void* const* d_in, const int* in_sizes, int n_in,
                              void* d_out, int out_size, void* d_ws,
                              size_t ws_size, hipStream_t stream) {
  const float* z0      = (const float*)d_in[0];
  const float* actions = (const float*)d_in[1];
  const float* W1  = (const float*)d_in[2];
  const float* b1  = (const float*)d_in[3];
  const float* g1  = (const float*)d_in[4];
  const float* be1 = (const float*)d_in[5];
  const float* W2  = (const float*)d_in[6];
  const float* b2  = (const float*)d_in[7];
  const float* g2  = (const float*)d_in[8];
  const float* be2 = (const float*)d_in[9];
  const float* W3  = (const float*)d_in[10];
  const float* b3  = (const float*)d_in[11];
  const float* uW1 = (const float*)d_in[12];
  const float* ub1 = (const float*)d_in[13];
  const float* uW2 = (const float*)d_in[14];
  const float* ub2 = (const float*)d_in[15];
  const float* gate = (const float*)d_in[16];

  char* w = (char*)d_ws;
  __hip_bfloat16* W1t = (__hip_bfloat16*)w;  w += (size_t)(L_SZ + A_SZ) * HD_SZ * 2;
  __hip_bfloat16* W2t = (__hip_bfloat16*)w;  w += (size_t)HD_SZ * HD_SZ * 2;
  __hip_bfloat16* W3t = (__hip_bfloat16*)w;  w += (size_t)HD_SZ * L_SZ * 2;
  __hip_bfloat16* uW1t = (__hip_bfloat16*)w; w += (size_t)L_SZ * (HD_SZ / 2) * 2;
  __hip_bfloat16* actb = (__hip_bfloat16*)w; w += (size_t)B_SZ * H_SZ * A_SZ * 2;
  float* z_cur = (float*)w;                  w += (size_t)B_SZ * L_SZ * 4;
  __hip_bfloat16* znb = (__hip_bfloat16*)w;  w += (size_t)B_SZ * L_SZ * 2;
  float* tws = (float*)w;                    w += (size_t)B_SZ * HD_SZ * 4;
  __hip_bfloat16* hb = (__hip_bfloat16*)w;   w += (size_t)B_SZ * HD_SZ * 2;
  float* sig_acc = (float*)w;                w += (size_t)B_SZ * H_SZ * 4;

  float* trajOut = (float*)d_out;
  float* sigsOut = (float*)d_out + (size_t)B_SZ * H_SZ * L_SZ;

  dim3 tb(32, 8);
  transpose_cvt<<<dim3(HD_SZ / 32, (L_SZ + A_SZ) / 32), tb, 0, stream>>>(W1, W1t, L_SZ + A_SZ, HD_SZ);
  transpose_cvt<<<dim3(HD_SZ / 32, HD_SZ / 32), tb, 0, stream>>>(W2, W2t, HD_SZ, HD_SZ);
  transpose_cvt<<<dim3(L_SZ / 32, HD_SZ / 32), tb, 0, stream>>>(W3, W3t, HD_SZ, L_SZ);
  transpose_cvt<<<dim3((HD_SZ / 2) / 32, L_SZ / 32), tb, 0, stream>>>(uW1, uW1t, L_SZ, HD_SZ / 2);

  cvt_bf16_kernel<<<(B_SZ * H_SZ * A_SZ / 4 + 255) / 256, 256, 0, stream>>>(
      actions, actb, B_SZ * H_SZ * A_SZ / 4);
  init_z_kernel<<<(B_SZ * L_SZ / 4 + 255) / 256, 256, 0, stream>>>(
      z0, z_cur, znb, B_SZ * L_SZ / 4);
  zero_kernel<<<(B_SZ * H_SZ + 255) / 256, 256, 0, stream>>>(sig_acc, B_SZ * H_SZ);

  const int KSPLIT_NONE = 1 << 30;
  for (int t = 0; t < H_SZ; ++t) {
    // GEMM1: za @ W1 + b1 -> tws   (A = [znb | actions[:,t,:]], ksplit=512)
    gemm_kernel<64, 128, 0><<<dim3(B_SZ / 64, HD_SZ / 128), 256, 0, stream>>>(
        znb, L_SZ, actb + (size_t)t * A_SZ, H_SZ * A_SZ, L_SZ, W1t, b1,
        HD_SZ, L_SZ + A_SZ, tws, nullptr, nullptr, nullptr, nullptr, 0,
        nullptr, nullptr);
    ln_gelu_kernel<<<B_SZ, 256, 0, stream>>>(tws, g1, be1, hb);
    // GEMM2: h1 @ W2 + b2 -> tws
    gemm_kernel<64, 128, 0><<<dim3(B_SZ / 64, HD_SZ / 128), 256, 0, stream>>>(
        hb, HD_SZ, nullptr, 0, KSPLIT_NONE, W2t, b2,
        HD_SZ, HD_SZ, tws, nullptr, nullptr, nullptr, nullptr, 0,
        nullptr, nullptr);
    ln_gelu_kernel<<<B_SZ, 256, 0, stream>>>(tws, g2, be2, hb);
    // GEMM3: h2 @ W3 + b3 -> z update + traj write + znb
    gemm_kernel<32, 128, 1><<<dim3(B_SZ / 32, L_SZ / 128), 256, 0, stream>>>(
        hb, HD_SZ, nullptr, 0, KSPLIT_NONE, W3t, b3,
        L_SZ, HD_SZ, nullptr, z_cur, znb, trajOut, gate, t,
        nullptr, nullptr);
    // GEMM4: z_next @ uW1 + ub1 -> gelu -> dot(uW2) partials -> sig_acc
    gemm_kernel<32, 128, 3><<<dim3(B_SZ / 32, (HD_SZ / 2) / 128), 256, 0, stream>>>(
        znb, L_SZ, nullptr, 0, KSPLIT_NONE, uW1t, ub1,
        HD_SZ / 2, L_SZ, nullptr, nullptr, nullptr, nullptr, nullptr, t,
        uW2, sig_acc);
  }
  softplus_kernel<<<(B_SZ * H_SZ + 255) / 256, 256, 0, stream>>>(
      sig_acc, ub2, sigsOut, B_SZ * H_SZ);
}